// Round 1
// baseline (1064.844 us; speedup 1.0000x reference)
//
#include <hip/hip_runtime.h>
#include <hip/hip_bf16.h>

#define NEG_SLOPE 0.01f
#define L2EPS 1e-12f
#define SCAN_CHUNK 2048

// ---------------- CSR build ----------------

__global__ void count_edges(const int* __restrict__ rows, int* __restrict__ counts, int nnz) {
    int i = blockIdx.x * blockDim.x + threadIdx.x;
    if (i < nnz) atomicAdd(&counts[rows[i]], 1);
}

__global__ void scan_sum(const int* __restrict__ counts, int* __restrict__ partials, int n) {
    __shared__ int red[256];
    int base = blockIdx.x * SCAN_CHUNK;
    int s = 0;
    for (int i = threadIdx.x; i < SCAN_CHUNK; i += 256) {
        int idx = base + i;
        s += (idx < n) ? counts[idx] : 0;
    }
    red[threadIdx.x] = s; __syncthreads();
    for (int o = 128; o > 0; o >>= 1) {
        if (threadIdx.x < o) red[threadIdx.x] += red[threadIdx.x + o];
        __syncthreads();
    }
    if (threadIdx.x == 0) partials[blockIdx.x] = red[0];
}

__global__ void scan_partials(int* __restrict__ partials, int nb, int* __restrict__ offsets, int n) {
    if (threadIdx.x == 0 && blockIdx.x == 0) {
        int run = 0;
        for (int i = 0; i < nb; i++) { int v = partials[i]; partials[i] = run; run += v; }
        offsets[n] = run;   // == NNZ
    }
}

__global__ void scan_apply(const int* __restrict__ counts, const int* __restrict__ partials,
                           int* __restrict__ offsets, int* __restrict__ cursor, int n) {
    __shared__ int lsum[256];
    int base = blockIdx.x * SCAN_CHUNK;
    int t = threadIdx.x;
    int my[8];
    int s = 0;
    int tb = base + t * 8;
    for (int i = 0; i < 8; i++) { int idx = tb + i; int v = (idx < n) ? counts[idx] : 0; my[i] = v; s += v; }
    lsum[t] = s; __syncthreads();
    // inclusive Hillis-Steele over 256 per-thread sums
    for (int o = 1; o < 256; o <<= 1) {
        int v = (t >= o) ? lsum[t - o] : 0;
        __syncthreads();
        lsum[t] += v;
        __syncthreads();
    }
    int excl = lsum[t] - s + partials[blockIdx.x];
    for (int i = 0; i < 8; i++) {
        int idx = tb + i;
        if (idx < n) { offsets[idx] = excl; cursor[idx] = excl; excl += my[i]; }
    }
}

__global__ void scatter_edges(const int* __restrict__ rows, const int* __restrict__ cols,
                              const float* __restrict__ vals, int* __restrict__ cursor,
                              int* __restrict__ pcols, float* __restrict__ pvals, int nnz) {
    int i = blockIdx.x * blockDim.x + threadIdx.x;
    if (i < nnz) {
        int r = rows[i];
        int p = atomicAdd(&cursor[r], 1);
        pcols[p] = cols[i];
        pvals[p] = vals[i];
    }
}

// ---------------- SpMM: side[r] = sum_j vals[j] * ego[cols[j]] ----------------
// D floats per row; D/4 lanes per row, float4 per lane.

template <int D>
__global__ void spmm_kernel(const float* __restrict__ ego, const int* __restrict__ offs,
                            const int* __restrict__ pcols, const float* __restrict__ pvals,
                            float* __restrict__ side, int nrows) {
    constexpr int LANES = D / 4;
    int gid = blockIdx.x * blockDim.x + threadIdx.x;
    int row = gid / LANES;
    int lane = gid % LANES;
    if (row >= nrows) return;
    int j0 = offs[row], j1 = offs[row + 1];
    float4 acc = make_float4(0.f, 0.f, 0.f, 0.f);
    for (int j = j0; j < j1; ++j) {
        int c = pcols[j];
        float v = pvals[j];
        float4 x = ((const float4*)(ego + (size_t)c * D))[lane];
        acc.x += v * x.x; acc.y += v * x.y; acc.z += v * x.z; acc.w += v * x.w;
    }
    ((float4*)(side + (size_t)row * D))[lane] = acc;
}

// ---------------- Dense bi-interaction + L2 norm ----------------
// ego_next = leaky((e+s)@w1+b1) + leaky((e*s)@w2+b2); out[:, col_off:col_off+DOUT] = l2norm(ego_next)

template <int DIN, int DOUT>
__global__ void dense_kernel(const float* __restrict__ ego, const float* __restrict__ side,
                             const float* __restrict__ w1, const float* __restrict__ b1,
                             const float* __restrict__ w2, const float* __restrict__ b2,
                             float* __restrict__ ego_next, float* __restrict__ outp,
                             int out_stride, int col_off, int nrows) {
    constexpr int RPB = 256 / DOUT;
    __shared__ float sE[RPB][DIN + 1];
    __shared__ float sS[RPB][DIN + 1];
    int t = threadIdx.x;
    int rl = t / DOUT;
    int tc = t % DOUT;
    int row = blockIdx.x * RPB + rl;
    if (row < nrows) {
        for (int k = tc; k < DIN; k += DOUT) {
            sE[rl][k] = ego[(size_t)row * DIN + k];
            sS[rl][k] = side[(size_t)row * DIN + k];
        }
    }
    __syncthreads();
    if (row >= nrows) return;

    float a1 = b1[tc], a2 = b2[tc];
#pragma unroll
    for (int k = 0; k < DIN; k++) {
        float e = sE[rl][k], s = sS[rl][k];
        a1 += (e + s) * w1[k * DOUT + tc];
        a2 += (e * s) * w2[k * DOUT + tc];
    }
    a1 = (a1 >= 0.f) ? a1 : NEG_SLOPE * a1;
    a2 = (a2 >= 0.f) ? a2 : NEG_SLOPE * a2;
    float x = a1 + a2;
    if (ego_next) ego_next[(size_t)row * DOUT + tc] = x;
    // L2 norm across the DOUT contiguous lanes of this row (within one wave)
    float ss = x * x;
#pragma unroll
    for (int o = DOUT >> 1; o > 0; o >>= 1) ss += __shfl_xor(ss, o, DOUT);
    float n = sqrtf(ss);
    float y = x / fmaxf(n, L2EPS);
    outp[(size_t)row * out_stride + col_off + tc] = y;
}

// ---------------- copy raw embeddings into output cols [0,64) ----------------

__global__ void copy_embed(const float* __restrict__ emb, float* __restrict__ outp, int nrows) {
    int idx = blockIdx.x * blockDim.x + threadIdx.x;
    int total = nrows * 16;   // float4s per row of 64
    if (idx >= total) return;
    int row = idx >> 4, c = idx & 15;
    float4 v = ((const float4*)emb)[idx];
    ((float4*)(outp + (size_t)row * 176))[c] = v;
}

extern "C" void kernel_launch(void* const* d_in, const int* in_sizes, int n_in,
                              void* d_out, int out_size, void* d_ws, size_t ws_size,
                              hipStream_t stream) {
    const float* emb   = (const float*)d_in[0];
    const float* avals = (const float*)d_in[1];
    const float* w1_0 = (const float*)d_in[2];  const float* b1_0 = (const float*)d_in[3];
    const float* w2_0 = (const float*)d_in[4];  const float* b2_0 = (const float*)d_in[5];
    const float* w1_1 = (const float*)d_in[6];  const float* b1_1 = (const float*)d_in[7];
    const float* w2_1 = (const float*)d_in[8];  const float* b2_1 = (const float*)d_in[9];
    const float* w1_2 = (const float*)d_in[10]; const float* b1_2 = (const float*)d_in[11];
    const float* w2_2 = (const float*)d_in[12]; const float* b2_2 = (const float*)d_in[13];
    const int* arows = (const int*)d_in[14];
    const int* acols = (const int*)d_in[15];
    float* outp = (float*)d_out;

    const int N   = in_sizes[0] / 64;     // 170000
    const int NNZ = in_sizes[14];         // 2720000

    // workspace carve-up (256B aligned)
    char* w = (char*)d_ws;
    size_t off = 0;
    auto carve = [&](size_t bytes) { char* p = w + off; off += (bytes + 255) & ~(size_t)255; return p; };
    int*   counts   = (int*)  carve((size_t)N * 4);
    int*   offsets  = (int*)  carve((size_t)(N + 1) * 4);
    int*   cursor   = (int*)  carve((size_t)N * 4);
    int*   partials = (int*)  carve(1024);
    int*   pcols    = (int*)  carve((size_t)NNZ * 4);
    float* pvals    = (float*)carve((size_t)NNZ * 4);
    float* side     = (float*)carve((size_t)N * 64 * 4);
    float* ego1     = (float*)carve((size_t)N * 64 * 4);
    float* ego2     = (float*)carve((size_t)N * 32 * 4);

    const int NB = (N + SCAN_CHUNK - 1) / SCAN_CHUNK;   // 84

    // ---- CSR build (once; shared by all 3 layers) ----
    hipMemsetAsync(counts, 0, (size_t)N * 4, stream);
    count_edges<<<(NNZ + 255) / 256, 256, 0, stream>>>(arows, counts, NNZ);
    scan_sum<<<NB, 256, 0, stream>>>(counts, partials, N);
    scan_partials<<<1, 64, 0, stream>>>(partials, NB, offsets, N);
    scan_apply<<<NB, 256, 0, stream>>>(counts, partials, offsets, cursor, N);
    scatter_edges<<<(NNZ + 255) / 256, 256, 0, stream>>>(arows, acols, avals, cursor, pcols, pvals, NNZ);

    // ---- output cols [0,64): raw embeddings ----
    copy_embed<<<(N * 16 + 255) / 256, 256, 0, stream>>>(emb, outp, N);

    // ---- layer 0: 64 -> 64 ----
    spmm_kernel<64><<<((size_t)N * 16 + 255) / 256, 256, 0, stream>>>(emb, offsets, pcols, pvals, side, N);
    dense_kernel<64, 64><<<(N + 3) / 4, 256, 0, stream>>>(emb, side, w1_0, b1_0, w2_0, b2_0,
                                                          ego1, outp, 176, 64, N);
    // ---- layer 1: 64 -> 32 ----
    spmm_kernel<64><<<((size_t)N * 16 + 255) / 256, 256, 0, stream>>>(ego1, offsets, pcols, pvals, side, N);
    dense_kernel<64, 32><<<(N + 7) / 8, 256, 0, stream>>>(ego1, side, w1_1, b1_1, w2_1, b2_1,
                                                          ego2, outp, 176, 128, N);
    // ---- layer 2: 32 -> 16 ----
    spmm_kernel<32><<<((size_t)N * 8 + 255) / 256, 256, 0, stream>>>(ego2, offsets, pcols, pvals, side, N);
    dense_kernel<32, 16><<<(N + 15) / 16, 256, 0, stream>>>(ego2, side, w1_2, b1_2, w2_2, b2_2,
                                                            nullptr, outp, 176, 160, N);
}

// Round 2
// 939.041 us; speedup vs baseline: 1.1340x; 1.1340x over previous
//
#include <hip/hip_runtime.h>
#include <hip/hip_bf16.h>

#define NEG_SLOPE 0.01f
#define L2EPS 1e-12f
#define SCAN_CHUNK 2048

// ---------------- CSR build ----------------

__global__ void count_edges(const int* __restrict__ rows, int* __restrict__ counts, int nnz) {
    int i = blockIdx.x * blockDim.x + threadIdx.x;
    if (i < nnz) atomicAdd(&counts[rows[i]], 1);
}

__global__ void scan_sum(const int* __restrict__ counts, int* __restrict__ partials, int n) {
    __shared__ int red[256];
    int base = blockIdx.x * SCAN_CHUNK;
    int s = 0;
    for (int i = threadIdx.x; i < SCAN_CHUNK; i += 256) {
        int idx = base + i;
        s += (idx < n) ? counts[idx] : 0;
    }
    red[threadIdx.x] = s; __syncthreads();
    for (int o = 128; o > 0; o >>= 1) {
        if (threadIdx.x < o) red[threadIdx.x] += red[threadIdx.x + o];
        __syncthreads();
    }
    if (threadIdx.x == 0) partials[blockIdx.x] = red[0];
}

__global__ void scan_partials(int* __restrict__ partials, int nb, int* __restrict__ offsets, int n) {
    if (threadIdx.x == 0 && blockIdx.x == 0) {
        int run = 0;
        for (int i = 0; i < nb; i++) { int v = partials[i]; partials[i] = run; run += v; }
        offsets[n] = run;   // == NNZ
    }
}

__global__ void scan_apply(const int* __restrict__ counts, const int* __restrict__ partials,
                           int* __restrict__ offsets, int* __restrict__ cursor, int n) {
    __shared__ int lsum[256];
    int base = blockIdx.x * SCAN_CHUNK;
    int t = threadIdx.x;
    int my[8];
    int s = 0;
    int tb = base + t * 8;
    for (int i = 0; i < 8; i++) { int idx = tb + i; int v = (idx < n) ? counts[idx] : 0; my[i] = v; s += v; }
    lsum[t] = s; __syncthreads();
    for (int o = 1; o < 256; o <<= 1) {
        int v = (t >= o) ? lsum[t - o] : 0;
        __syncthreads();
        lsum[t] += v;
        __syncthreads();
    }
    int excl = lsum[t] - s + partials[blockIdx.x];
    for (int i = 0; i < 8; i++) {
        int idx = tb + i;
        if (idx < n) { offsets[idx] = excl; cursor[idx] = excl; excl += my[i]; }
    }
}

// packed edge: .x = col, .y = bit-cast val  (one 8B store instead of two 4B stores)
__global__ void scatter_edges(const int* __restrict__ rows, const int* __restrict__ cols,
                              const float* __restrict__ vals, int* __restrict__ cursor,
                              int2* __restrict__ pedge, int nnz) {
    int i = blockIdx.x * blockDim.x + threadIdx.x;
    if (i < nnz) {
        int r = rows[i];
        int p = atomicAdd(&cursor[r], 1);
        pedge[p] = make_int2(cols[i], __float_as_int(vals[i]));
    }
}

// ---------------- SpMM: side[r] = sum_j vals[j] * ego[cols[j]] ----------------

template <int D>
__global__ void spmm_kernel(const float* __restrict__ ego, const int* __restrict__ offs,
                            const int2* __restrict__ pedge, float* __restrict__ side, int nrows) {
    constexpr int LANES = D / 4;
    int gid = blockIdx.x * blockDim.x + threadIdx.x;
    int row = gid / LANES;
    int lane = gid % LANES;
    if (row >= nrows) return;
    int j0 = offs[row], j1 = offs[row + 1];
    float4 acc = make_float4(0.f, 0.f, 0.f, 0.f);
    for (int j = j0; j < j1; ++j) {
        int2 e = pedge[j];
        float v = __int_as_float(e.y);
        float4 x = ((const float4*)(ego + (size_t)e.x * D))[lane];
        acc.x += v * x.x; acc.y += v * x.y; acc.z += v * x.z; acc.w += v * x.w;
    }
    ((float4*)(side + (size_t)row * D))[lane] = acc;
}

// ---------------- Dense bi-interaction + L2 norm (register-tiled) ----------------
// Per block: 64 rows. Stage W1,W2 in LDS; stage U=e+s and V=e*s TRANSPOSED in LDS
// (sU[k][row], pad +4 keeps 16B alignment for ds_read_b128). Thread computes a
// 4-row x 4-col tile: per k, 4 x b128 LDS reads feed 32 FMAs (VALU-bound).

__device__ __forceinline__ float leaky1(float x) { return x >= 0.f ? x : NEG_SLOPE * x; }

template <int DIN, int DOUT>
__global__ void dense_kernel(const float* __restrict__ ego, const float* __restrict__ side,
                             const float* __restrict__ w1, const float* __restrict__ b1,
                             const float* __restrict__ w2, const float* __restrict__ b2,
                             float* __restrict__ ego_next, float* __restrict__ outp,
                             int col_off, int nrows) {
    constexpr int RPB = 64;             // rows per block
    constexpr int TX = DOUT / 4;        // threads across cols
    constexpr int TY = 16;              // threads across rows (4 rows each)
    constexpr int NT = TX * TY;         // block size: 256 / 128 / 64
    constexpr int LD4 = DIN / 4;        // float4s per row
    constexpr int RPP = NT / LD4;       // rows staged per pass

    __shared__ float sU[DIN][RPB + 4];
    __shared__ float sV[DIN][RPB + 4];
    __shared__ float sW1[DIN * DOUT];
    __shared__ float sW2[DIN * DOUT];

    int tid = threadIdx.x;
    int row0 = blockIdx.x * RPB;

    // stage weights
    for (int i = tid; i < DIN * DOUT / 4; i += NT) {
        ((float4*)sW1)[i] = ((const float4*)w1)[i];
        ((float4*)sW2)[i] = ((const float4*)w2)[i];
    }
    // stage U,V transposed
    {
        int kq = tid % LD4, rr = tid / LD4;
        for (int r = rr; r < RPB; r += RPP) {
            int g = row0 + r;
            if (g < nrows) {
                float4 e = ((const float4*)(ego + (size_t)g * DIN))[kq];
                float4 s = ((const float4*)(side + (size_t)g * DIN))[kq];
                sU[kq * 4 + 0][r] = e.x + s.x;
                sU[kq * 4 + 1][r] = e.y + s.y;
                sU[kq * 4 + 2][r] = e.z + s.z;
                sU[kq * 4 + 3][r] = e.w + s.w;
                sV[kq * 4 + 0][r] = e.x * s.x;
                sV[kq * 4 + 1][r] = e.y * s.y;
                sV[kq * 4 + 2][r] = e.z * s.z;
                sV[kq * 4 + 3][r] = e.w * s.w;
            }
        }
    }
    __syncthreads();

    int tx = tid % TX, ty = tid / TX;
    float4 a1[4], a2[4];
#pragma unroll
    for (int i = 0; i < 4; i++) {
        a1[i] = make_float4(0.f, 0.f, 0.f, 0.f);
        a2[i] = make_float4(0.f, 0.f, 0.f, 0.f);
    }

#pragma unroll 8
    for (int k = 0; k < DIN; k++) {
        float4 w1v = *(const float4*)&sW1[k * DOUT + tx * 4];
        float4 w2v = *(const float4*)&sW2[k * DOUT + tx * 4];
        float4 uv = *(const float4*)&sU[k][ty * 4];
        float4 vv = *(const float4*)&sV[k][ty * 4];
        a1[0].x += uv.x * w1v.x; a1[0].y += uv.x * w1v.y; a1[0].z += uv.x * w1v.z; a1[0].w += uv.x * w1v.w;
        a1[1].x += uv.y * w1v.x; a1[1].y += uv.y * w1v.y; a1[1].z += uv.y * w1v.z; a1[1].w += uv.y * w1v.w;
        a1[2].x += uv.z * w1v.x; a1[2].y += uv.z * w1v.y; a1[2].z += uv.z * w1v.z; a1[2].w += uv.z * w1v.w;
        a1[3].x += uv.w * w1v.x; a1[3].y += uv.w * w1v.y; a1[3].z += uv.w * w1v.z; a1[3].w += uv.w * w1v.w;
        a2[0].x += vv.x * w2v.x; a2[0].y += vv.x * w2v.y; a2[0].z += vv.x * w2v.z; a2[0].w += vv.x * w2v.w;
        a2[1].x += vv.y * w2v.x; a2[1].y += vv.y * w2v.y; a2[1].z += vv.y * w2v.z; a2[1].w += vv.y * w2v.w;
        a2[2].x += vv.z * w2v.x; a2[2].y += vv.z * w2v.y; a2[2].z += vv.z * w2v.z; a2[2].w += vv.z * w2v.w;
        a2[3].x += vv.w * w2v.x; a2[3].y += vv.w * w2v.y; a2[3].z += vv.w * w2v.z; a2[3].w += vv.w * w2v.w;
    }

    float4 bb1 = ((const float4*)b1)[tx];
    float4 bb2 = ((const float4*)b2)[tx];
#pragma unroll
    for (int i = 0; i < 4; i++) {
        int g = row0 + ty * 4 + i;
        float4 x;
        x.x = leaky1(a1[i].x + bb1.x) + leaky1(a2[i].x + bb2.x);
        x.y = leaky1(a1[i].y + bb1.y) + leaky1(a2[i].y + bb2.y);
        x.z = leaky1(a1[i].z + bb1.z) + leaky1(a2[i].z + bb2.z);
        x.w = leaky1(a1[i].w + bb1.w) + leaky1(a2[i].w + bb2.w);
        float ss = x.x * x.x + x.y * x.y + x.z * x.z + x.w * x.w;
#pragma unroll
        for (int o = TX >> 1; o > 0; o >>= 1) ss += __shfl_xor(ss, o, 64);
        if (g < nrows) {
            if (ego_next) ((float4*)(ego_next + (size_t)g * DOUT))[tx] = x;
            float inv = 1.f / fmaxf(sqrtf(ss), L2EPS);
            float4 y = make_float4(x.x * inv, x.y * inv, x.z * inv, x.w * inv);
            ((float4*)(outp + (size_t)g * 176 + col_off))[tx] = y;
        }
    }
}

// ---------------- copy raw embeddings into output cols [0,64) ----------------

__global__ void copy_embed(const float* __restrict__ emb, float* __restrict__ outp, int nrows) {
    int idx = blockIdx.x * blockDim.x + threadIdx.x;
    int total = nrows * 16;
    if (idx >= total) return;
    int row = idx >> 4, c = idx & 15;
    float4 v = ((const float4*)emb)[idx];
    ((float4*)(outp + (size_t)row * 176))[c] = v;
}

extern "C" void kernel_launch(void* const* d_in, const int* in_sizes, int n_in,
                              void* d_out, int out_size, void* d_ws, size_t ws_size,
                              hipStream_t stream) {
    const float* emb   = (const float*)d_in[0];
    const float* avals = (const float*)d_in[1];
    const float* w1_0 = (const float*)d_in[2];  const float* b1_0 = (const float*)d_in[3];
    const float* w2_0 = (const float*)d_in[4];  const float* b2_0 = (const float*)d_in[5];
    const float* w1_1 = (const float*)d_in[6];  const float* b1_1 = (const float*)d_in[7];
    const float* w2_1 = (const float*)d_in[8];  const float* b2_1 = (const float*)d_in[9];
    const float* w1_2 = (const float*)d_in[10]; const float* b1_2 = (const float*)d_in[11];
    const float* w2_2 = (const float*)d_in[12]; const float* b2_2 = (const float*)d_in[13];
    const int* arows = (const int*)d_in[14];
    const int* acols = (const int*)d_in[15];
    float* outp = (float*)d_out;

    const int N   = in_sizes[0] / 64;     // 170000
    const int NNZ = in_sizes[14];         // 2720000

    char* w = (char*)d_ws;
    size_t off = 0;
    auto carve = [&](size_t bytes) { char* p = w + off; off += (bytes + 255) & ~(size_t)255; return p; };
    int*   counts   = (int*)  carve((size_t)N * 4);
    int*   offsets  = (int*)  carve((size_t)(N + 1) * 4);
    int*   cursor   = (int*)  carve((size_t)N * 4);
    int*   partials = (int*)  carve(1024);
    int2*  pedge    = (int2*) carve((size_t)NNZ * 8);
    float* side     = (float*)carve((size_t)N * 64 * 4);
    float* ego1     = (float*)carve((size_t)N * 64 * 4);
    float* ego2     = (float*)carve((size_t)N * 32 * 4);

    const int NB = (N + SCAN_CHUNK - 1) / SCAN_CHUNK;

    // ---- CSR build (once; shared by all 3 layers) ----
    hipMemsetAsync(counts, 0, (size_t)N * 4, stream);
    count_edges<<<(NNZ + 255) / 256, 256, 0, stream>>>(arows, counts, NNZ);
    scan_sum<<<NB, 256, 0, stream>>>(counts, partials, N);
    scan_partials<<<1, 64, 0, stream>>>(partials, NB, offsets, N);
    scan_apply<<<NB, 256, 0, stream>>>(counts, partials, offsets, cursor, N);
    scatter_edges<<<(NNZ + 255) / 256, 256, 0, stream>>>(arows, acols, avals, cursor, pedge, NNZ);

    // ---- output cols [0,64): raw embeddings ----
    copy_embed<<<(N * 16 + 255) / 256, 256, 0, stream>>>(emb, outp, N);

    const int DB = (N + 63) / 64;   // dense blocks (64 rows each)

    // ---- layer 0: 64 -> 64 ----
    spmm_kernel<64><<<((size_t)N * 16 + 255) / 256, 256, 0, stream>>>(emb, offsets, pedge, side, N);
    dense_kernel<64, 64><<<DB, 256, 0, stream>>>(emb, side, w1_0, b1_0, w2_0, b2_0, ego1, outp, 64, N);
    // ---- layer 1: 64 -> 32 ----
    spmm_kernel<64><<<((size_t)N * 16 + 255) / 256, 256, 0, stream>>>(ego1, offsets, pedge, side, N);
    dense_kernel<64, 32><<<DB, 128, 0, stream>>>(ego1, side, w1_1, b1_1, w2_1, b2_1, ego2, outp, 128, N);
    // ---- layer 2: 32 -> 16 ----
    spmm_kernel<32><<<((size_t)N * 8 + 255) / 256, 256, 0, stream>>>(ego2, offsets, pedge, side, N);
    dense_kernel<32, 16><<<DB, 64, 0, stream>>>(ego2, side, w1_2, b1_2, w2_2, b2_2, nullptr, outp, 160, N);
}

// Round 3
// 860.894 us; speedup vs baseline: 1.2369x; 1.0908x over previous
//
#include <hip/hip_runtime.h>
#include <hip/hip_bf16.h>

#define NEG_SLOPE 0.01f
#define L2EPS 1e-12f
#define SCAN_CHUNK 2048
#define PART_CH 16384          // edges per partition chunk
#define BSHIFT 9               // 512 rows per bucket

// ---------------- generic exclusive scan (3 kernels) ----------------

__global__ void count_edges(const int* __restrict__ rows, int* __restrict__ counts, int nnz) {
    int i = blockIdx.x * blockDim.x + threadIdx.x;
    if (i < nnz) atomicAdd(&counts[rows[i]], 1);
}

__global__ void scan_sum(const int* __restrict__ counts, int* __restrict__ partials, int n) {
    __shared__ int red[256];
    int base = blockIdx.x * SCAN_CHUNK;
    int s = 0;
    for (int i = threadIdx.x; i < SCAN_CHUNK; i += 256) {
        int idx = base + i;
        s += (idx < n) ? counts[idx] : 0;
    }
    red[threadIdx.x] = s; __syncthreads();
    for (int o = 128; o > 0; o >>= 1) {
        if (threadIdx.x < o) red[threadIdx.x] += red[threadIdx.x + o];
        __syncthreads();
    }
    if (threadIdx.x == 0) partials[blockIdx.x] = red[0];
}

__global__ void scan_partials(int* __restrict__ partials, int nb, int* __restrict__ out, int n) {
    if (threadIdx.x == 0 && blockIdx.x == 0) {
        int run = 0;
        for (int i = 0; i < nb; i++) { int v = partials[i]; partials[i] = run; run += v; }
        out[n] = run;
    }
}

__global__ void scan_apply(const int* __restrict__ counts, const int* __restrict__ partials,
                           int* __restrict__ out, int n) {
    __shared__ int lsum[256];
    int base = blockIdx.x * SCAN_CHUNK;
    int t = threadIdx.x;
    int my[8];
    int s = 0;
    int tb = base + t * 8;
    for (int i = 0; i < 8; i++) { int idx = tb + i; int v = (idx < n) ? counts[idx] : 0; my[i] = v; s += v; }
    lsum[t] = s; __syncthreads();
    for (int o = 1; o < 256; o <<= 1) {
        int v = (t >= o) ? lsum[t - o] : 0;
        __syncthreads();
        lsum[t] += v;
        __syncthreads();
    }
    int excl = lsum[t] - s + partials[blockIdx.x];
    for (int i = 0; i < 8; i++) {
        int idx = tb + i;
        if (idx < n) { out[idx] = excl; excl += my[i]; }
    }
}

// ---------------- two-pass radix partition into CSR order ----------------
// pass A: per-chunk bucket histogram (bucket = row >> BSHIFT)
__global__ void part_hist(const int* __restrict__ rows, int* __restrict__ hist,
                          int nnz, int nchunks, int B) {
    __shared__ int h[512];
    int c = blockIdx.x;
    for (int i = threadIdx.x; i < B; i += 256) h[i] = 0;
    __syncthreads();
    int s = c * PART_CH, e = min(s + PART_CH, nnz);
    for (int i = s + threadIdx.x; i < e; i += 256) atomicAdd(&h[rows[i] >> BSHIFT], 1);
    __syncthreads();
    for (int b = threadIdx.x; b < B; b += 256) hist[b * nchunks + c] = h[b];
}

// pass B: scatter edges into bucket-contiguous tmp (contiguous runs per bucket per chunk)
__global__ void part_scatter(const int* __restrict__ rows, const int* __restrict__ cols,
                             const float* __restrict__ vals, const int* __restrict__ hscan,
                             int2* __restrict__ tmp, int nnz, int nchunks, int B) {
    __shared__ int cur[512];
    int c = blockIdx.x;
    for (int b = threadIdx.x; b < B; b += 256) cur[b] = hscan[b * nchunks + c];
    __syncthreads();
    int s = c * PART_CH, e = min(s + PART_CH, nnz);
    for (int i = s + threadIdx.x; i < e; i += 256) {
        int r = rows[i];
        int p = atomicAdd(&cur[r >> BSHIFT], 1);
        tmp[p] = make_int2(((r & 511) << 18) | cols[i], __float_as_int(vals[i]));
    }
}

// pass C: within each bucket (64 KB dest window, L2-resident) scatter to exact CSR slot
__global__ void bucket_scatter(const int* __restrict__ hscan, const int* __restrict__ offsets,
                               const int2* __restrict__ tmp, int2* __restrict__ pedge,
                               int nnz, int nchunks, int B, int n) {
    __shared__ int cur[512];
    int b = blockIdx.x;
    int rbase = b << BSHIFT;
    for (int r = threadIdx.x; r < 512; r += 256) {
        int g = rbase + r;
        cur[r] = (g < n) ? offsets[g] : 0;
    }
    __syncthreads();
    int s = hscan[b * nchunks];
    int e = (b == B - 1) ? nnz : hscan[(b + 1) * nchunks];
    for (int j = s + threadIdx.x; j < e; j += 256) {
        int2 t = tmp[j];
        int r9 = ((unsigned)t.x) >> 18;
        int p = atomicAdd(&cur[r9], 1);
        pedge[p] = make_int2(t.x & 0x3FFFF, t.y);
    }
}

// ---------------- SpMM: side[r] = sum_j vals[j] * ego[cols[j]] ----------------

template <int D>
__global__ void spmm_kernel(const float* __restrict__ ego, const int* __restrict__ offs,
                            const int2* __restrict__ pedge, float* __restrict__ side, int nrows) {
    constexpr int LANES = D / 4;
    int gid = blockIdx.x * blockDim.x + threadIdx.x;
    int row = gid / LANES;
    int lane = gid % LANES;
    if (row >= nrows) return;
    int j0 = offs[row], j1 = offs[row + 1];
    float4 acc = make_float4(0.f, 0.f, 0.f, 0.f);
    for (int j = j0; j < j1; ++j) {
        int2 e = pedge[j];
        float v = __int_as_float(e.y);
        float4 x = ((const float4*)(ego + (size_t)e.x * D))[lane];
        acc.x += v * x.x; acc.y += v * x.y; acc.z += v * x.z; acc.w += v * x.w;
    }
    ((float4*)(side + (size_t)row * D))[lane] = acc;
}

// ---------------- Dense bi-interaction + L2 norm (register-tiled) ----------------

__device__ __forceinline__ float leaky1(float x) { return x >= 0.f ? x : NEG_SLOPE * x; }

template <int DIN, int DOUT>
__global__ void dense_kernel(const float* __restrict__ ego, const float* __restrict__ side,
                             const float* __restrict__ w1, const float* __restrict__ b1,
                             const float* __restrict__ w2, const float* __restrict__ b2,
                             float* __restrict__ ego_next, float* __restrict__ outp,
                             int col_off, int nrows) {
    constexpr int RPB = 64;
    constexpr int TX = DOUT / 4;
    constexpr int TY = 16;
    constexpr int NT = TX * TY;
    constexpr int LD4 = DIN / 4;
    constexpr int RPP = NT / LD4;

    __shared__ float sU[DIN][RPB + 4];
    __shared__ float sV[DIN][RPB + 4];
    __shared__ float sW1[DIN * DOUT];
    __shared__ float sW2[DIN * DOUT];

    int tid = threadIdx.x;
    int row0 = blockIdx.x * RPB;

    for (int i = tid; i < DIN * DOUT / 4; i += NT) {
        ((float4*)sW1)[i] = ((const float4*)w1)[i];
        ((float4*)sW2)[i] = ((const float4*)w2)[i];
    }
    {
        int kq = tid % LD4, rr = tid / LD4;
        for (int r = rr; r < RPB; r += RPP) {
            int g = row0 + r;
            if (g < nrows) {
                float4 e = ((const float4*)(ego + (size_t)g * DIN))[kq];
                float4 s = ((const float4*)(side + (size_t)g * DIN))[kq];
                sU[kq * 4 + 0][r] = e.x + s.x;
                sU[kq * 4 + 1][r] = e.y + s.y;
                sU[kq * 4 + 2][r] = e.z + s.z;
                sU[kq * 4 + 3][r] = e.w + s.w;
                sV[kq * 4 + 0][r] = e.x * s.x;
                sV[kq * 4 + 1][r] = e.y * s.y;
                sV[kq * 4 + 2][r] = e.z * s.z;
                sV[kq * 4 + 3][r] = e.w * s.w;
            }
        }
    }
    __syncthreads();

    int tx = tid % TX, ty = tid / TX;
    float4 a1[4], a2[4];
#pragma unroll
    for (int i = 0; i < 4; i++) {
        a1[i] = make_float4(0.f, 0.f, 0.f, 0.f);
        a2[i] = make_float4(0.f, 0.f, 0.f, 0.f);
    }

#pragma unroll 8
    for (int k = 0; k < DIN; k++) {
        float4 w1v = *(const float4*)&sW1[k * DOUT + tx * 4];
        float4 w2v = *(const float4*)&sW2[k * DOUT + tx * 4];
        float4 uv = *(const float4*)&sU[k][ty * 4];
        float4 vv = *(const float4*)&sV[k][ty * 4];
        a1[0].x += uv.x * w1v.x; a1[0].y += uv.x * w1v.y; a1[0].z += uv.x * w1v.z; a1[0].w += uv.x * w1v.w;
        a1[1].x += uv.y * w1v.x; a1[1].y += uv.y * w1v.y; a1[1].z += uv.y * w1v.z; a1[1].w += uv.y * w1v.w;
        a1[2].x += uv.z * w1v.x; a1[2].y += uv.z * w1v.y; a1[2].z += uv.z * w1v.z; a1[2].w += uv.z * w1v.w;
        a1[3].x += uv.w * w1v.x; a1[3].y += uv.w * w1v.y; a1[3].z += uv.w * w1v.z; a1[3].w += uv.w * w1v.w;
        a2[0].x += vv.x * w2v.x; a2[0].y += vv.x * w2v.y; a2[0].z += vv.x * w2v.z; a2[0].w += vv.x * w2v.w;
        a2[1].x += vv.y * w2v.x; a2[1].y += vv.y * w2v.y; a2[1].z += vv.y * w2v.z; a2[1].w += vv.y * w2v.w;
        a2[2].x += vv.z * w2v.x; a2[2].y += vv.z * w2v.y; a2[2].z += vv.z * w2v.z; a2[2].w += vv.z * w2v.w;
        a2[3].x += vv.w * w2v.x; a2[3].y += vv.w * w2v.y; a2[3].z += vv.w * w2v.z; a2[3].w += vv.w * w2v.w;
    }

    float4 bb1 = ((const float4*)b1)[tx];
    float4 bb2 = ((const float4*)b2)[tx];
#pragma unroll
    for (int i = 0; i < 4; i++) {
        int g = row0 + ty * 4 + i;
        float4 x;
        x.x = leaky1(a1[i].x + bb1.x) + leaky1(a2[i].x + bb2.x);
        x.y = leaky1(a1[i].y + bb1.y) + leaky1(a2[i].y + bb2.y);
        x.z = leaky1(a1[i].z + bb1.z) + leaky1(a2[i].z + bb2.z);
        x.w = leaky1(a1[i].w + bb1.w) + leaky1(a2[i].w + bb2.w);
        float ss = x.x * x.x + x.y * x.y + x.z * x.z + x.w * x.w;
#pragma unroll
        for (int o = TX >> 1; o > 0; o >>= 1) ss += __shfl_xor(ss, o, 64);
        if (g < nrows) {
            if (ego_next) ((float4*)(ego_next + (size_t)g * DOUT))[tx] = x;
            float inv = 1.f / fmaxf(sqrtf(ss), L2EPS);
            float4 y = make_float4(x.x * inv, x.y * inv, x.z * inv, x.w * inv);
            ((float4*)(outp + (size_t)g * 176 + col_off))[tx] = y;
        }
    }
}

// ---------------- copy raw embeddings into output cols [0,64) ----------------

__global__ void copy_embed(const float* __restrict__ emb, float* __restrict__ outp, int nrows) {
    int idx = blockIdx.x * blockDim.x + threadIdx.x;
    int total = nrows * 16;
    if (idx >= total) return;
    int row = idx >> 4, c = idx & 15;
    float4 v = ((const float4*)emb)[idx];
    ((float4*)(outp + (size_t)row * 176))[c] = v;
}

extern "C" void kernel_launch(void* const* d_in, const int* in_sizes, int n_in,
                              void* d_out, int out_size, void* d_ws, size_t ws_size,
                              hipStream_t stream) {
    const float* emb   = (const float*)d_in[0];
    const float* avals = (const float*)d_in[1];
    const float* w1_0 = (const float*)d_in[2];  const float* b1_0 = (const float*)d_in[3];
    const float* w2_0 = (const float*)d_in[4];  const float* b2_0 = (const float*)d_in[5];
    const float* w1_1 = (const float*)d_in[6];  const float* b1_1 = (const float*)d_in[7];
    const float* w2_1 = (const float*)d_in[8];  const float* b2_1 = (const float*)d_in[9];
    const float* w1_2 = (const float*)d_in[10]; const float* b1_2 = (const float*)d_in[11];
    const float* w2_2 = (const float*)d_in[12]; const float* b2_2 = (const float*)d_in[13];
    const int* arows = (const int*)d_in[14];
    const int* acols = (const int*)d_in[15];
    float* outp = (float*)d_out;

    const int N   = in_sizes[0] / 64;     // 170000
    const int NNZ = in_sizes[14];         // 2720000

    const int B       = (N + 511) >> BSHIFT;            // 333 buckets
    const int nchunks = (NNZ + PART_CH - 1) / PART_CH;  // 166
    const int NH      = B * nchunks;                    // hist elements

    char* w = (char*)d_ws;
    size_t off = 0;
    auto carve = [&](size_t bytes) { char* p = w + off; off += (bytes + 255) & ~(size_t)255; return p; };
    int*   counts   = (int*)  carve((size_t)N * 4);
    int*   offsets  = (int*)  carve((size_t)(N + 1) * 4);
    int*   partials = (int*)  carve(1024);
    int*   hist     = (int*)  carve((size_t)(NH + 1) * 4);
    int*   hscan    = (int*)  carve((size_t)(NH + 1) * 4);
    int2*  pedge    = (int2*) carve((size_t)NNZ * 8);
    float* side     = (float*)carve((size_t)N * 64 * 4);
    float* ego1     = (float*)carve((size_t)N * 64 * 4);
    float* ego2     = (float*)carve((size_t)N * 32 * 4);
    int2*  tmp      = (int2*)side;   // alias: side is first written after bucket_scatter

    const int NB  = (N + SCAN_CHUNK - 1) / SCAN_CHUNK;
    const int NB2 = (NH + SCAN_CHUNK - 1) / SCAN_CHUNK;

    // ---- CSR offsets ----
    hipMemsetAsync(counts, 0, (size_t)N * 4, stream);
    count_edges<<<(NNZ + 255) / 256, 256, 0, stream>>>(arows, counts, NNZ);
    scan_sum<<<NB, 256, 0, stream>>>(counts, partials, N);
    scan_partials<<<1, 64, 0, stream>>>(partials, NB, offsets, N);
    scan_apply<<<NB, 256, 0, stream>>>(counts, partials, offsets, N);

    // ---- two-pass partition into CSR-ordered pedge ----
    part_hist<<<nchunks, 256, 0, stream>>>(arows, hist, NNZ, nchunks, B);
    scan_sum<<<NB2, 256, 0, stream>>>(hist, partials, NH);
    scan_partials<<<1, 64, 0, stream>>>(partials, NB2, hscan, NH);
    scan_apply<<<NB2, 256, 0, stream>>>(hist, partials, hscan, NH);
    part_scatter<<<nchunks, 256, 0, stream>>>(arows, acols, avals, hscan, tmp, NNZ, nchunks, B);
    bucket_scatter<<<B, 256, 0, stream>>>(hscan, offsets, tmp, pedge, NNZ, nchunks, B, N);

    // ---- output cols [0,64): raw embeddings ----
    copy_embed<<<(N * 16 + 255) / 256, 256, 0, stream>>>(emb, outp, N);

    const int DB = (N + 63) / 64;

    // ---- layer 0: 64 -> 64 ----
    spmm_kernel<64><<<((size_t)N * 16 + 255) / 256, 256, 0, stream>>>(emb, offsets, pedge, side, N);
    dense_kernel<64, 64><<<DB, 256, 0, stream>>>(emb, side, w1_0, b1_0, w2_0, b2_0, ego1, outp, 64, N);
    // ---- layer 1: 64 -> 32 ----
    spmm_kernel<64><<<((size_t)N * 16 + 255) / 256, 256, 0, stream>>>(ego1, offsets, pedge, side, N);
    dense_kernel<64, 32><<<DB, 128, 0, stream>>>(ego1, side, w1_1, b1_1, w2_1, b2_1, ego2, outp, 128, N);
    // ---- layer 2: 32 -> 16 ----
    spmm_kernel<32><<<((size_t)N * 8 + 255) / 256, 256, 0, stream>>>(ego2, offsets, pedge, side, N);
    dense_kernel<32, 16><<<DB, 64, 0, stream>>>(ego2, side, w1_2, b1_2, w2_2, b2_2, nullptr, outp, 160, N);
}

// Round 4
// 661.538 us; speedup vs baseline: 1.6096x; 1.3014x over previous
//
#include <hip/hip_runtime.h>
#include <hip/hip_bf16.h>

#define NEG_SLOPE 0.01f
#define L2EPS 1e-12f
#define SCAN_CHUNK 2048
#define PART_CH 8192           // edges per partition chunk
#define BSHIFT 9               // 512 rows per bucket

__device__ __forceinline__ unsigned short f2bf(float f) {   // RNE float->bf16
    unsigned u = __float_as_uint(f);
    return (unsigned short)((u + 0x7fffu + ((u >> 16) & 1u)) >> 16);
}

// ---------------- generic exclusive scan (for chunk histograms) ----------------

__global__ void scan_sum(const int* __restrict__ counts, int* __restrict__ partials, int n) {
    __shared__ int red[256];
    int base = blockIdx.x * SCAN_CHUNK;
    int s = 0;
    for (int i = threadIdx.x; i < SCAN_CHUNK; i += 256) {
        int idx = base + i;
        s += (idx < n) ? counts[idx] : 0;
    }
    red[threadIdx.x] = s; __syncthreads();
    for (int o = 128; o > 0; o >>= 1) {
        if (threadIdx.x < o) red[threadIdx.x] += red[threadIdx.x + o];
        __syncthreads();
    }
    if (threadIdx.x == 0) partials[blockIdx.x] = red[0];
}

__global__ void scan_partials(int* __restrict__ partials, int nb, int* __restrict__ out, int n) {
    if (threadIdx.x == 0 && blockIdx.x == 0) {
        int run = 0;
        for (int i = 0; i < nb; i++) { int v = partials[i]; partials[i] = run; run += v; }
        out[n] = run;
    }
}

__global__ void scan_apply(const int* __restrict__ counts, const int* __restrict__ partials,
                           int* __restrict__ out, int n) {
    __shared__ int lsum[256];
    int base = blockIdx.x * SCAN_CHUNK;
    int t = threadIdx.x;
    int my[8];
    int s = 0;
    int tb = base + t * 8;
    for (int i = 0; i < 8; i++) { int idx = tb + i; int v = (idx < n) ? counts[idx] : 0; my[i] = v; s += v; }
    lsum[t] = s; __syncthreads();
    for (int o = 1; o < 256; o <<= 1) {
        int v = (t >= o) ? lsum[t - o] : 0;
        __syncthreads();
        lsum[t] += v;
        __syncthreads();
    }
    int excl = lsum[t] - s + partials[blockIdx.x];
    for (int i = 0; i < 8; i++) {
        int idx = tb + i;
        if (idx < n) { out[idx] = excl; excl += my[i]; }
    }
}

// ---------------- two-pass radix partition into CSR order ----------------

__global__ void part_hist(const int* __restrict__ rows, int* __restrict__ hist,
                          int nnz, int nchunks, int B) {
    __shared__ int h[512];
    int c = blockIdx.x;
    for (int i = threadIdx.x; i < B; i += 256) h[i] = 0;
    __syncthreads();
    int s = c * PART_CH, e = min(s + PART_CH, nnz);
    for (int i = s + threadIdx.x; i < e; i += 256) atomicAdd(&h[rows[i] >> BSHIFT], 1);
    __syncthreads();
    for (int b = threadIdx.x; b < B; b += 256) hist[b * nchunks + c] = h[b];
}

__global__ void part_scatter(const int* __restrict__ rows, const int* __restrict__ cols,
                             const float* __restrict__ vals, const int* __restrict__ hscan,
                             int2* __restrict__ tmp, int nnz, int nchunks, int B) {
    __shared__ int cur[512];
    int c = blockIdx.x;
    for (int b = threadIdx.x; b < B; b += 256) cur[b] = hscan[b * nchunks + c];
    __syncthreads();
    int s = c * PART_CH, e = min(s + PART_CH, nnz);
    for (int i = s + threadIdx.x; i < e; i += 256) {
        int r = rows[i];
        int p = atomicAdd(&cur[r >> BSHIFT], 1);
        tmp[p] = make_int2(((r & 511) << 18) | cols[i], __float_as_int(vals[i]));
    }
}

// fused: per-bucket row histogram -> LDS scan -> emits offsets[] AND CSR-ordered pedge
__global__ void bucket_scatter(const int* __restrict__ hscan, const int2* __restrict__ tmp,
                               int2* __restrict__ pedge, int* __restrict__ offsets,
                               int nnz, int nchunks, int B, int n) {
    __shared__ int cnt[512];
    __shared__ int scn[256];
    int b = blockIdx.x;
    int t = threadIdx.x;
    int rbase = b << BSHIFT;
    cnt[t] = 0; cnt[t + 256] = 0;
    __syncthreads();
    int s = hscan[b * nchunks];
    int e = (b == B - 1) ? nnz : hscan[(b + 1) * nchunks];
    for (int j = s + t; j < e; j += 256) atomicAdd(&cnt[((unsigned)tmp[j].x) >> 18], 1);
    __syncthreads();
    int c0 = cnt[2 * t], c1 = cnt[2 * t + 1];
    int ssum = c0 + c1;
    scn[t] = ssum;
    __syncthreads();
    for (int o = 1; o < 256; o <<= 1) {
        int v = (t >= o) ? scn[t - o] : 0;
        __syncthreads();
        scn[t] += v;
        __syncthreads();
    }
    int excl = scn[t] - ssum + s;   // global CSR position of row rbase+2t
    int g0 = rbase + 2 * t, g1 = g0 + 1;
    if (g0 < n) offsets[g0] = excl;
    if (g1 < n) offsets[g1] = excl + c0;
    cnt[2 * t] = excl;
    cnt[2 * t + 1] = excl + c0;
    if (b == B - 1 && t == 0) offsets[n] = nnz;
    __syncthreads();
    for (int j = s + t; j < e; j += 256) {
        int2 tt = tmp[j];
        int r9 = ((unsigned)tt.x) >> 18;
        int p = atomicAdd(&cnt[r9], 1);
        pedge[p] = make_int2(tt.x & 0x3FFFF, tt.y);
    }
}

// ---------------- fp32 -> bf16 table convert ----------------

__global__ void to_bf16(const float* __restrict__ src, unsigned short* __restrict__ dst, int n4) {
    int i = blockIdx.x * blockDim.x + threadIdx.x;
    if (i >= n4) return;
    float4 v = ((const float4*)src)[i];
    ushort4 o;
    o.x = f2bf(v.x); o.y = f2bf(v.y); o.z = f2bf(v.z); o.w = f2bf(v.w);
    ((ushort4*)dst)[i] = o;
}

// ---------------- SpMM (bf16 gather, fp32 accumulate) ----------------
// D/8 lanes per row; each lane loads uint4 = 8 bf16 (16 B).

template <int D>
__global__ void spmm_kernel(const unsigned short* __restrict__ egob, const int* __restrict__ offs,
                            const int2* __restrict__ pedge, float* __restrict__ side, int nrows) {
    constexpr int LANES = D / 8;
    int gid = blockIdx.x * blockDim.x + threadIdx.x;
    int row = gid / LANES;
    int lane = gid % LANES;
    if (row >= nrows) return;
    int j0 = offs[row], j1 = offs[row + 1];
    float acc[8] = {0.f, 0.f, 0.f, 0.f, 0.f, 0.f, 0.f, 0.f};
    for (int j = j0; j < j1; ++j) {
        int2 ed = pedge[j];
        float v = __int_as_float(ed.y);
        uint4 q = ((const uint4*)(egob + (size_t)ed.x * D))[lane];
        acc[0] += v * __uint_as_float(q.x << 16);
        acc[1] += v * __uint_as_float(q.x & 0xffff0000u);
        acc[2] += v * __uint_as_float(q.y << 16);
        acc[3] += v * __uint_as_float(q.y & 0xffff0000u);
        acc[4] += v * __uint_as_float(q.z << 16);
        acc[5] += v * __uint_as_float(q.z & 0xffff0000u);
        acc[6] += v * __uint_as_float(q.w << 16);
        acc[7] += v * __uint_as_float(q.w & 0xffff0000u);
    }
    float4* sp = (float4*)(side + (size_t)row * D + lane * 8);
    sp[0] = make_float4(acc[0], acc[1], acc[2], acc[3]);
    sp[1] = make_float4(acc[4], acc[5], acc[6], acc[7]);
}

// ---------------- Dense bi-interaction + L2 norm (register-tiled) ----------------

__device__ __forceinline__ float leaky1(float x) { return x >= 0.f ? x : NEG_SLOPE * x; }

template <int DIN, int DOUT>
__global__ void dense_kernel(const float* __restrict__ ego, const float* __restrict__ side,
                             const float* __restrict__ w1, const float* __restrict__ b1,
                             const float* __restrict__ w2, const float* __restrict__ b2,
                             float* __restrict__ ego_next, unsigned short* __restrict__ egob_next,
                             float* __restrict__ outp, int col_off, int nrows) {
    constexpr int RPB = 64;
    constexpr int TX = DOUT / 4;
    constexpr int TY = 16;
    constexpr int NT = TX * TY;
    constexpr int LD4 = DIN / 4;
    constexpr int RPP = NT / LD4;

    __shared__ float sU[DIN][RPB + 4];
    __shared__ float sV[DIN][RPB + 4];
    __shared__ float sW1[DIN * DOUT];
    __shared__ float sW2[DIN * DOUT];

    int tid = threadIdx.x;
    int row0 = blockIdx.x * RPB;

    for (int i = tid; i < DIN * DOUT / 4; i += NT) {
        ((float4*)sW1)[i] = ((const float4*)w1)[i];
        ((float4*)sW2)[i] = ((const float4*)w2)[i];
    }
    {
        int kq = tid % LD4, rr = tid / LD4;
        for (int r = rr; r < RPB; r += RPP) {
            int g = row0 + r;
            if (g < nrows) {
                float4 e = ((const float4*)(ego + (size_t)g * DIN))[kq];
                float4 s = ((const float4*)(side + (size_t)g * DIN))[kq];
                sU[kq * 4 + 0][r] = e.x + s.x;
                sU[kq * 4 + 1][r] = e.y + s.y;
                sU[kq * 4 + 2][r] = e.z + s.z;
                sU[kq * 4 + 3][r] = e.w + s.w;
                sV[kq * 4 + 0][r] = e.x * s.x;
                sV[kq * 4 + 1][r] = e.y * s.y;
                sV[kq * 4 + 2][r] = e.z * s.z;
                sV[kq * 4 + 3][r] = e.w * s.w;
            }
        }
    }
    __syncthreads();

    int tx = tid % TX, ty = tid / TX;
    float4 a1[4], a2[4];
#pragma unroll
    for (int i = 0; i < 4; i++) {
        a1[i] = make_float4(0.f, 0.f, 0.f, 0.f);
        a2[i] = make_float4(0.f, 0.f, 0.f, 0.f);
    }

#pragma unroll 8
    for (int k = 0; k < DIN; k++) {
        float4 w1v = *(const float4*)&sW1[k * DOUT + tx * 4];
        float4 w2v = *(const float4*)&sW2[k * DOUT + tx * 4];
        float4 uv = *(const float4*)&sU[k][ty * 4];
        float4 vv = *(const float4*)&sV[k][ty * 4];
        a1[0].x += uv.x * w1v.x; a1[0].y += uv.x * w1v.y; a1[0].z += uv.x * w1v.z; a1[0].w += uv.x * w1v.w;
        a1[1].x += uv.y * w1v.x; a1[1].y += uv.y * w1v.y; a1[1].z += uv.y * w1v.z; a1[1].w += uv.y * w1v.w;
        a1[2].x += uv.z * w1v.x; a1[2].y += uv.z * w1v.y; a1[2].z += uv.z * w1v.z; a1[2].w += uv.z * w1v.w;
        a1[3].x += uv.w * w1v.x; a1[3].y += uv.w * w1v.y; a1[3].z += uv.w * w1v.z; a1[3].w += uv.w * w1v.w;
        a2[0].x += vv.x * w2v.x; a2[0].y += vv.x * w2v.y; a2[0].z += vv.x * w2v.z; a2[0].w += vv.x * w2v.w;
        a2[1].x += vv.y * w2v.x; a2[1].y += vv.y * w2v.y; a2[1].z += vv.y * w2v.z; a2[1].w += vv.y * w2v.w;
        a2[2].x += vv.z * w2v.x; a2[2].y += vv.z * w2v.y; a2[2].z += vv.z * w2v.z; a2[2].w += vv.z * w2v.w;
        a2[3].x += vv.w * w2v.x; a2[3].y += vv.w * w2v.y; a2[3].z += vv.w * w2v.z; a2[3].w += vv.w * w2v.w;
    }

    float4 bb1 = ((const float4*)b1)[tx];
    float4 bb2 = ((const float4*)b2)[tx];
#pragma unroll
    for (int i = 0; i < 4; i++) {
        int g = row0 + ty * 4 + i;
        float4 x;
        x.x = leaky1(a1[i].x + bb1.x) + leaky1(a2[i].x + bb2.x);
        x.y = leaky1(a1[i].y + bb1.y) + leaky1(a2[i].y + bb2.y);
        x.z = leaky1(a1[i].z + bb1.z) + leaky1(a2[i].z + bb2.z);
        x.w = leaky1(a1[i].w + bb1.w) + leaky1(a2[i].w + bb2.w);
        float ss = x.x * x.x + x.y * x.y + x.z * x.z + x.w * x.w;
#pragma unroll
        for (int o = TX >> 1; o > 0; o >>= 1) ss += __shfl_xor(ss, o, 64);
        if (g < nrows) {
            if (ego_next) {
                ((float4*)(ego_next + (size_t)g * DOUT))[tx] = x;
                ushort4 xb;
                xb.x = f2bf(x.x); xb.y = f2bf(x.y); xb.z = f2bf(x.z); xb.w = f2bf(x.w);
                ((ushort4*)(egob_next + (size_t)g * DOUT))[tx] = xb;
            }
            float inv = 1.f / fmaxf(sqrtf(ss), L2EPS);
            float4 y = make_float4(x.x * inv, x.y * inv, x.z * inv, x.w * inv);
            ((float4*)(outp + (size_t)g * 176 + col_off))[tx] = y;
        }
    }
}

// ---------------- copy raw embeddings into output cols [0,64) ----------------

__global__ void copy_embed(const float* __restrict__ emb, float* __restrict__ outp, int nrows) {
    int idx = blockIdx.x * blockDim.x + threadIdx.x;
    int total = nrows * 16;
    if (idx >= total) return;
    int row = idx >> 4, c = idx & 15;
    float4 v = ((const float4*)emb)[idx];
    ((float4*)(outp + (size_t)row * 176))[c] = v;
}

extern "C" void kernel_launch(void* const* d_in, const int* in_sizes, int n_in,
                              void* d_out, int out_size, void* d_ws, size_t ws_size,
                              hipStream_t stream) {
    const float* emb   = (const float*)d_in[0];
    const float* avals = (const float*)d_in[1];
    const float* w1_0 = (const float*)d_in[2];  const float* b1_0 = (const float*)d_in[3];
    const float* w2_0 = (const float*)d_in[4];  const float* b2_0 = (const float*)d_in[5];
    const float* w1_1 = (const float*)d_in[6];  const float* b1_1 = (const float*)d_in[7];
    const float* w2_1 = (const float*)d_in[8];  const float* b2_1 = (const float*)d_in[9];
    const float* w1_2 = (const float*)d_in[10]; const float* b1_2 = (const float*)d_in[11];
    const float* w2_2 = (const float*)d_in[12]; const float* b2_2 = (const float*)d_in[13];
    const int* arows = (const int*)d_in[14];
    const int* acols = (const int*)d_in[15];
    float* outp = (float*)d_out;

    const int N   = in_sizes[0] / 64;     // 170000
    const int NNZ = in_sizes[14];         // 2720000

    const int B       = (N + 511) >> BSHIFT;            // 333 buckets
    const int nchunks = (NNZ + PART_CH - 1) / PART_CH;  // 332
    const int NH      = B * nchunks;

    char* w = (char*)d_ws;
    size_t off = 0;
    auto carve = [&](size_t bytes) { char* p = w + off; off += (bytes + 255) & ~(size_t)255; return p; };
    int*   offsets  = (int*)  carve((size_t)(N + 1) * 4);
    int*   partials = (int*)  carve(1024);
    int*   hist     = (int*)  carve((size_t)(NH + 1) * 4);
    int*   hscan    = (int*)  carve((size_t)(NH + 1) * 4);
    int2*  pedge    = (int2*) carve((size_t)NNZ * 8);
    float* side     = (float*)carve((size_t)N * 64 * 4);
    float* ego1     = (float*)carve((size_t)N * 64 * 4);
    float* ego2     = (float*)carve((size_t)N * 32 * 4);
    unsigned short* egob = (unsigned short*)carve((size_t)N * 64 * 2);  // reused across layers
    int2*  tmp      = (int2*)side;   // alias: side first written after bucket_scatter

    const int NB2 = (NH + SCAN_CHUNK - 1) / SCAN_CHUNK;

    // ---- partition into CSR-ordered pedge; bucket_scatter also emits offsets ----
    part_hist<<<nchunks, 256, 0, stream>>>(arows, hist, NNZ, nchunks, B);
    scan_sum<<<NB2, 256, 0, stream>>>(hist, partials, NH);
    scan_partials<<<1, 64, 0, stream>>>(partials, NB2, hscan, NH);
    scan_apply<<<NB2, 256, 0, stream>>>(hist, partials, hscan, NH);
    part_scatter<<<nchunks, 256, 0, stream>>>(arows, acols, avals, hscan, tmp, NNZ, nchunks, B);
    bucket_scatter<<<B, 256, 0, stream>>>(hscan, tmp, pedge, offsets, NNZ, nchunks, B, N);

    // ---- bf16 gather table for layer 0 + raw-embedding output copy ----
    to_bf16<<<(N * 16 + 255) / 256, 256, 0, stream>>>(emb, egob, N * 16);
    copy_embed<<<(N * 16 + 255) / 256, 256, 0, stream>>>(emb, outp, N);

    const int DB = (N + 63) / 64;

    // ---- layer 0: 64 -> 64 ----
    spmm_kernel<64><<<((size_t)N * 8 + 255) / 256, 256, 0, stream>>>(egob, offsets, pedge, side, N);
    dense_kernel<64, 64><<<DB, 256, 0, stream>>>(emb, side, w1_0, b1_0, w2_0, b2_0, ego1, egob, outp, 64, N);
    // ---- layer 1: 64 -> 32 ----
    spmm_kernel<64><<<((size_t)N * 8 + 255) / 256, 256, 0, stream>>>(egob, offsets, pedge, side, N);
    dense_kernel<64, 32><<<DB, 128, 0, stream>>>(ego1, side, w1_1, b1_1, w2_1, b2_1, ego2, egob, outp, 128, N);
    // ---- layer 2: 32 -> 16 ----
    spmm_kernel<32><<<((size_t)N * 4 + 255) / 256, 256, 0, stream>>>(egob, offsets, pedge, side, N);
    dense_kernel<32, 16><<<DB, 64, 0, stream>>>(ego2, side, w1_2, b1_2, w2_2, b2_2, nullptr, nullptr, outp, 160, N);
}